// Round 10
// baseline (941.955 us; speedup 1.0000x reference)
//
#include <hip/hip_runtime.h>
#include <math.h>

typedef unsigned short ushort;
typedef unsigned int uint;
typedef __bf16 bf16x8 __attribute__((ext_vector_type(8)));
typedef float f32x4 __attribute__((ext_vector_type(4)));

// Problem constants
#define ZS    128
#define KS    256
#define HS    512
#define BATCH 512
#define TT    32
#define MM    33
#define NB    2304      // 2048 gate cols (n = j*4+gate) + 256 key cols
#define KPAD  800       // 0..256 key_r, 257..271 zero pad, 272..783 h, 784..799 pad
#define HOFF  272
#define LDA   800

static __device__ __forceinline__ float sigf(float x) { return 1.f / (1.f + expf(-x)); }
static __device__ __forceinline__ float bf2f(ushort u) { return __uint_as_float((uint)u << 16); }

// ---------------------------------------------------------------------------
// Weight prep: Whi/Wlo [2304][800] bf16 (n-major, k-contig); Behi/Belo
// [128][1024] from W_enc transposed; biasN fused.
// ---------------------------------------------------------------------------
__global__ void prep_w(const float* __restrict__ W_ih, const float* __restrict__ W_hh,
                       const float* __restrict__ W_key, const float* __restrict__ b_ih,
                       const float* __restrict__ b_hh, const float* __restrict__ b_key,
                       const float* __restrict__ W_enc,
                       ushort* __restrict__ Whi, ushort* __restrict__ Wlo,
                       ushort* __restrict__ Behi, ushort* __restrict__ Belo,
                       float* __restrict__ biasN)
{
    int idx = blockIdx.x * 256 + threadIdx.x;
    if (idx < NB) {
        float bv;
        if (idx < 2048) { int j = idx >> 2, gi = idx & 3, r = gi * 512 + j; bv = b_ih[r] + b_hh[r]; }
        else bv = b_key[idx - 2048];
        biasN[idx] = bv;
    }
    if (idx < NB * KPAD) {
        int n = idx / KPAD, k = idx - n * KPAD;
        float v = 0.f;
        if (n < 2048) {
            int j = n >> 2, gi = n & 3, r = gi * 512 + j;
            if (k < 257) v = W_ih[r * 257 + k];
            else if (k >= HOFF && k < HOFF + 512) v = W_hh[r * 512 + (k - HOFF)];
        } else {
            if (k >= HOFF && k < HOFF + 512) v = W_key[(n - 2048) * 512 + (k - HOFF)];
        }
        uint u = __float_as_uint(v);
        Whi[idx] = (ushort)(u >> 16);
        float lo = v - __uint_as_float(u & 0xFFFF0000u);
        Wlo[idx] = (ushort)(__float_as_uint(lo) >> 16);
    } else if (idx < NB * KPAD + 128 * 1024) {
        int e = idx - NB * KPAD;
        int n = e >> 10, k = e & 1023;
        float v = W_enc[k * 128 + n];
        uint u = __float_as_uint(v);
        Behi[e] = (ushort)(u >> 16);
        float lo = v - __uint_as_float(u & 0xFFFF0000u);
        Belo[e] = (ushort)(__float_as_uint(lo) >> 16);
    }
}

// ---------------------------------------------------------------------------
// Encoder GEMM: BM=32 x BN=128, fp32 A split on the fly, grid 512, nslice=32.
// R10 change: LOADG(s+1) issued AFTER __syncthreads (the barrier's vmcnt(0)
// drain was forcing a full HBM-latency stall on the just-issued loads at
// every slice; issuing after the barrier overlaps the latency with COMPUTE,
// and the counted vmcnt wait lands at STORE).
// ---------------------------------------------------------------------------
__global__ __launch_bounds__(256, 4)
void gemm_enc(const float* __restrict__ A,
              const ushort* __restrict__ Bhi, const ushort* __restrict__ Blo,
              float* __restrict__ out)
{
    constexpr int BN = 128, NI = 4;
    constexpr int AHI = 0, ALO = 32 * 40, BHI = 64 * 40, BLO = 64 * 40 + BN * 40;
    constexpr int BUF = 64 * 40 + 2 * BN * 40;
    __shared__ ushort lds[2 * BUF];
    const int tid = threadIdx.x;
    const int row0 = blockIdx.x * 32, n0 = 0;
    const int lda = 1024, ldb = 1024, nslice = 32;
    const int l = tid & 63, w = tid >> 6, wm = w >> 1, wn = w & 1;
    const int lm = l & 15, kg = (l >> 4) << 3;

    f32x4 acc[NI];
    const f32x4 zero4 = {0.f, 0.f, 0.f, 0.f};
#pragma unroll
    for (int ni = 0; ni < NI; ni++) acc[ni] = zero4;

    float4 avf;
    uint4 bhv[BN / 64], blv[BN / 64];

    auto LOADG = [&](int s) {
        const int k0 = s * 32;
        int r = tid >> 3, c = (tid & 7) << 2;
        avf = *(const float4*)(A + (size_t)(row0 + r) * lda + k0 + c);
#pragma unroll
        for (int i = 0; i < BN / 64; i++) {
            int idx = tid + 256 * i, r2 = idx >> 2, c2 = (idx & 3) << 3;
            bhv[i] = *(const uint4*)(Bhi + (size_t)(n0 + r2) * ldb + k0 + c2);
            blv[i] = *(const uint4*)(Blo + (size_t)(n0 + r2) * ldb + k0 + c2);
        }
    };
    auto STORE = [&](int buf) {
        ushort* L = lds + buf * BUF;
        int r = tid >> 3, c = (tid & 7) << 2;
        uint u0 = __float_as_uint(avf.x), u1 = __float_as_uint(avf.y);
        uint u2 = __float_as_uint(avf.z), u3 = __float_as_uint(avf.w);
        uint hp0 = (u1 & 0xFFFF0000u) | (u0 >> 16);
        uint hp1 = (u3 & 0xFFFF0000u) | (u2 >> 16);
        float l0 = avf.x - __uint_as_float(u0 & 0xFFFF0000u);
        float l1 = avf.y - __uint_as_float(u1 & 0xFFFF0000u);
        float l2 = avf.z - __uint_as_float(u2 & 0xFFFF0000u);
        float l3 = avf.w - __uint_as_float(u3 & 0xFFFF0000u);
        uint lp0 = (__float_as_uint(l1) & 0xFFFF0000u) | (__float_as_uint(l0) >> 16);
        uint lp1 = (__float_as_uint(l3) & 0xFFFF0000u) | (__float_as_uint(l2) >> 16);
        *(uint2*)&L[AHI + r * 40 + c] = make_uint2(hp0, hp1);
        *(uint2*)&L[ALO + r * 40 + c] = make_uint2(lp0, lp1);
#pragma unroll
        for (int i = 0; i < BN / 64; i++) {
            int idx = tid + 256 * i, r2 = idx >> 2, c2 = (idx & 3) << 3;
            *(uint4*)&L[BHI + r2 * 40 + c2] = bhv[i];
            *(uint4*)&L[BLO + r2 * 40 + c2] = blv[i];
        }
    };
    auto COMPUTE = [&](int buf) {
        const ushort* L = lds + buf * BUF;
        bf16x8 ah, alv, bh[NI], bl[NI];
        {
            int r = wm * 16 + lm;
            ah  = *(const bf16x8*)&L[AHI + r * 40 + kg];
            alv = *(const bf16x8*)&L[ALO + r * 40 + kg];
        }
#pragma unroll
        for (int ni = 0; ni < NI; ni++) {
            int r = wn * (BN / 2) + ni * 16 + lm;
            bh[ni] = *(const bf16x8*)&L[BHI + r * 40 + kg];
            bl[ni] = *(const bf16x8*)&L[BLO + r * 40 + kg];
        }
#pragma unroll
        for (int ni = 0; ni < NI; ni++) {
            acc[ni] = __builtin_amdgcn_mfma_f32_16x16x32_bf16(ah,  bh[ni], acc[ni], 0, 0, 0);
            acc[ni] = __builtin_amdgcn_mfma_f32_16x16x32_bf16(ah,  bl[ni], acc[ni], 0, 0, 0);
            acc[ni] = __builtin_amdgcn_mfma_f32_16x16x32_bf16(alv, bh[ni], acc[ni], 0, 0, 0);
        }
    };

    LOADG(0);
    STORE(0);
    for (int s = 0; s < nslice; s++) {
        __syncthreads();
        if (s + 1 < nslice) LOADG(s + 1);   // in flight during COMPUTE(s)
        COMPUTE(s & 1);
        if (s + 1 < nslice) STORE((s + 1) & 1);  // vmcnt wait overlapped
    }

    const int crow = (l >> 4) << 2;   // C/D: row = (lane>>4)*4 + reg, col = lane&15
#pragma unroll
    for (int ni = 0; ni < NI; ni++)
#pragma unroll
        for (int r = 0; r < 4; r++) {
            int m = row0 + wm * 16 + crow + r;
            int z = n0 + wn * (BN / 2) + ni * 16 + lm;
            out[(size_t)(m >> 5) * (MM * ZS) + (m & 31) * ZS + z] = acc[ni][r];
        }
}

// ---------------------------------------------------------------------------
// Step GEMM: BM=64 x BN=64, 4 waves 2x2, wave tile 32x32 (0.67 LDS reads/MFMA
// — R9's win). K-SPLIT z=2 (slices 0..12 / 13..24), flat grid 576 = 8 XCDs *
// 72, XCD-contiguous swizzle (weights L2-resident).
// R10 change: LOADG(s+1) AFTER __syncthreads (see gemm_enc comment) — the
// barrier drain was exposing full L2 latency at each of the 13 slices.
// ---------------------------------------------------------------------------
__global__ __launch_bounds__(256, 4)
void gemm_step(const ushort* __restrict__ Ahi, const ushort* __restrict__ Alo,
               const ushort* __restrict__ Whi, const ushort* __restrict__ Wlo,
               float* __restrict__ P0, float* __restrict__ P1)
{
    constexpr int AHI = 0, ALO = 64 * 40, BHI = 128 * 40, BLO = 192 * 40;
    constexpr int BUF = 256 * 40;          // 10240 ushorts = 20KB per buffer
    __shared__ ushort lds[2 * BUF];
    const int tid = threadIdx.x;
    int wg = blockIdx.x;
    int swz = (wg & 7) * 72 + (wg >> 3);   // 576 = 8 XCDs * 72, bijective
    int zz = swz / 288;
    int rr = swz - zz * 288;
    const int bx = rr >> 3, by = rr & 7;   // bx 0..35 (N tiles), by 0..7 (M tiles)
    const int kb = zz ? 13 : 0, kc = zz ? 12 : 13;
    float* __restrict__ out = zz ? P1 : P0;
    const int row0 = by * 64, n0 = bx * 64;
    const int l = tid & 63, w = tid >> 6, wm = w >> 1, wn = w & 1;
    const int lm = l & 15, kg = (l >> 4) << 3;
    const int ar = tid >> 2, ac = (tid & 3) << 3;   // staging row/col (64 rows x 4 uint4)

    f32x4 acc[2][2];
    const f32x4 zero4 = {0.f, 0.f, 0.f, 0.f};
    acc[0][0] = zero4; acc[0][1] = zero4; acc[1][0] = zero4; acc[1][1] = zero4;

    uint4 av0, av1, bv0, bv1;

    auto LOADG = [&](int a) {
        const int k0 = a * 32;
        av0 = *(const uint4*)(Ahi + (size_t)(row0 + ar) * LDA + k0 + ac);
        av1 = *(const uint4*)(Alo + (size_t)(row0 + ar) * LDA + k0 + ac);
        bv0 = *(const uint4*)(Whi + (size_t)(n0 + ar) * KPAD + k0 + ac);
        bv1 = *(const uint4*)(Wlo + (size_t)(n0 + ar) * KPAD + k0 + ac);
    };
    auto STORE = [&](int buf) {
        ushort* L = lds + buf * BUF;
        int off = ar * 40 + ac;
        *(uint4*)&L[AHI + off] = av0;
        *(uint4*)&L[ALO + off] = av1;
        *(uint4*)&L[BHI + off] = bv0;
        *(uint4*)&L[BLO + off] = bv1;
    };
    auto COMPUTE = [&](int buf) {
        const ushort* L = lds + buf * BUF;
        bf16x8 ah[2], al[2], bh[2], bl[2];
#pragma unroll
        for (int mi = 0; mi < 2; mi++) {
            int r = wm * 32 + mi * 16 + lm;
            ah[mi] = *(const bf16x8*)&L[AHI + r * 40 + kg];
            al[mi] = *(const bf16x8*)&L[ALO + r * 40 + kg];
        }
#pragma unroll
        for (int ni = 0; ni < 2; ni++) {
            int r = wn * 32 + ni * 16 + lm;
            bh[ni] = *(const bf16x8*)&L[BHI + r * 40 + kg];
            bl[ni] = *(const bf16x8*)&L[BLO + r * 40 + kg];
        }
#pragma unroll
        for (int mi = 0; mi < 2; mi++)
#pragma unroll
            for (int ni = 0; ni < 2; ni++) {
                acc[mi][ni] = __builtin_amdgcn_mfma_f32_16x16x32_bf16(ah[mi], bh[ni], acc[mi][ni], 0, 0, 0);
                acc[mi][ni] = __builtin_amdgcn_mfma_f32_16x16x32_bf16(ah[mi], bl[ni], acc[mi][ni], 0, 0, 0);
                acc[mi][ni] = __builtin_amdgcn_mfma_f32_16x16x32_bf16(al[mi], bh[ni], acc[mi][ni], 0, 0, 0);
            }
    };

    LOADG(kb);
    STORE(0);
    for (int s = 0; s < kc; s++) {
        __syncthreads();
        if (s + 1 < kc) LOADG(kb + s + 1);       // in flight during COMPUTE(s)
        COMPUTE(s & 1);
        if (s + 1 < kc) STORE((s + 1) & 1);      // vmcnt wait overlapped
    }

    const int crow = (l >> 4) << 2;   // C/D: row = (lane>>4)*4 + reg, col = lane&15
#pragma unroll
    for (int mi = 0; mi < 2; mi++)
#pragma unroll
        for (int ni = 0; ni < 2; ni++)
#pragma unroll
            for (int r = 0; r < 4; r++) {
                int b = row0 + wm * 32 + mi * 16 + crow + r;
                int n = n0 + wn * 32 + ni * 16 + lm;
                out[(size_t)b * NB + n] = acc[mi][ni][r];
            }
}

// ---------------------------------------------------------------------------
// Fused per-step cell: sums K-split partials, bias, LSTM cell, h write
// (bf16 hi/lo), key relu -> Mk, then g-gate + attention read -> key_r(t+1).
// One block per batch row. Mk row t-1 consumed from register.
// ---------------------------------------------------------------------------
__global__ __launch_bounds__(256)
void cell_k(const float* __restrict__ P0, const float* __restrict__ P1,
            const float* __restrict__ biasN, float* __restrict__ cst,
            ushort* __restrict__ outHi, ushort* __restrict__ outLo,
            float* __restrict__ Mk,
            const float* __restrict__ W_g, const float* __restrict__ b_g,
            const float* __restrict__ watt, const float* __restrict__ wc,
            int t)
{
    __shared__ float hsh[512];
    __shared__ float red[256];
    __shared__ float wts[32];
    __shared__ float gsh;
    int b = blockIdx.x, tid = threadIdx.x;
    const float* p0 = P0 + (size_t)b * NB;
    const float* p1 = P1 + (size_t)b * NB;
    ushort* rHi = outHi + (size_t)b * LDA;
    ushort* rLo = outLo + (size_t)b * LDA;
#pragma unroll
    for (int u = 0; u < 2; u++) {
        int j = tid + u * 256;                 // hidden unit
        float4 a  = *(const float4*)(p0 + 4 * j);
        float4 c4 = *(const float4*)(p1 + 4 * j);
        float4 bb = *(const float4*)(biasN + 4 * j);
        float gi = a.x + c4.x + bb.x;          // PyTorch gate order i,f,g,o
        float gf = a.y + c4.y + bb.y;
        float gg = a.z + c4.z + bb.z;
        float go = a.w + c4.w + bb.w;
        float iv = sigf(gi), fv = sigf(gf), gv = tanhf(gg), ov = sigf(go);
        float cn = fv * cst[(size_t)b * HS + j] + iv * gv;
        float hv = ov * tanhf(cn);
        cst[(size_t)b * HS + j] = cn;
        hsh[j] = hv;
        uint uu = __float_as_uint(hv);
        rHi[HOFF + j] = (ushort)(uu >> 16);
        float lo = hv - __uint_as_float(uu & 0xFFFF0000u);
        rLo[HOFF + j] = (ushort)(__float_as_uint(lo) >> 16);
    }
    // key col k = tid
    float kv = fmaxf(p0[2048 + tid] + p1[2048 + tid] + biasN[2048 + tid], 0.f);
    if (t >= 1) Mk[((size_t)(t - 1) * BATCH + b) * KS + tid] = kv;
    if (t < 1 || t > 31) return;               // no attention read needed
    if (tid < t) wts[tid] = watt[(b * MM + t) * MM + tid];
    __syncthreads();
    red[tid] = hsh[tid] * W_g[tid] + hsh[tid + 256] * W_g[tid + 256];
    __syncthreads();
    for (int s = 128; s > 0; s >>= 1) {
        if (tid < s) red[tid] += red[tid + s];
        __syncthreads();
    }
    if (tid == 0) gsh = sigf(red[0] + b_g[0]);
    __syncthreads();
    float g = gsh;
    float acc = wts[t - 1] * kv;               // freshest Mk row from register
    for (int m = 0; m < t - 1; m++)
        acc += wts[m] * Mk[((size_t)m * BATCH + b) * KS + tid];
    float v = g * acc;
    uint u2 = __float_as_uint(v);
    rHi[tid] = (ushort)(u2 >> 16);
    float lo2 = v - __uint_as_float(u2 & 0xFFFF0000u);
    rLo[tid] = (ushort)(__float_as_uint(lo2) >> 16);
    if (tid == 0) {
        float vc = g * wc[b * MM + t];
        uint uc = __float_as_uint(vc);
        rHi[256] = (ushort)(uc >> 16);
        float lc = vc - __uint_as_float(uc & 0xFFFF0000u);
        rLo[256] = (ushort)(__float_as_uint(lc) >> 16);
    }
}

// ---------------------------------------------------------------------------
// Context norm over T, writes zero row t=32. (R0 form.)
// ---------------------------------------------------------------------------
__global__ void norm_k(float* __restrict__ z_pad, const float* __restrict__ gamma,
                       const float* __restrict__ beta)
{
    int b = blockIdx.x, zc = threadIdx.x;
    float* zb = z_pad + (size_t)b * (MM * ZS);
    float s = 0.f, s2 = 0.f;
    for (int t = 0; t < TT; t++) { float v = zb[t * ZS + zc]; s += v; s2 += v * v; }
    float mu = s * (1.f / 32.f);
    float var = s2 * (1.f / 32.f) - mu * mu;
    float rstd = 1.f / sqrtf(var + 1e-8f);
    float ga = gamma[zc], be = beta[zc];
    for (int t = 0; t < TT; t++) {
        float v = zb[t * ZS + zc];
        zb[t * ZS + zc] = (v - mu) * rstd * ga + be;
    }
    zb[TT * ZS + zc] = 0.f;
}

// ---------------------------------------------------------------------------
// Precompute attention weights + confidence sums (z-only, loop-invariant).
// ---------------------------------------------------------------------------
__global__ __launch_bounds__(256)
void scores_k(const float* __restrict__ z_pad, const float* __restrict__ cg_p,
              const float* __restrict__ cb_p, float* __restrict__ watt,
              float* __restrict__ wc)
{
    __shared__ float zs[MM * 129];
    int b = blockIdx.x, tid = threadIdx.x;
    const float* zb = z_pad + (size_t)b * (MM * ZS);
    for (int i = tid; i < MM * ZS; i += 256) {
        int m = i >> 7, k = i & 127;
        zs[m * 129 + k] = zb[i];
    }
    __syncthreads();
    float cg = cg_p[0], cb = cb_p[0];
    int wid = tid >> 6, lane = tid & 63;
    for (int t = 1 + wid; t <= 32; t += 4) {
        int m = lane;
        float s = -3.0e38f;
        if (m < t) {
            const float* zt = &zs[t * 129];
            const float* zm = &zs[m * 129];
            float acc = 0.f;
#pragma unroll 8
            for (int k = 0; k < ZS; k++) acc += zt[k] * zm[k];
            s = acc;
        }
        float mx = s;
        for (int off = 1; off < 64; off <<= 1) mx = fmaxf(mx, __shfl_xor(mx, off));
        float e = (m < t) ? expf(s - mx) : 0.f;
        float sum = e;
        for (int off = 1; off < 64; off <<= 1) sum += __shfl_xor(sum, off);
        float w = e / sum;
        if (m < t) watt[(b * MM + t) * MM + m] = w;
        float p = (m < t) ? w * sigf(s * cg + cb) : 0.f;
        for (int off = 1; off < 64; off <<= 1) p += __shfl_xor(p, off);
        if (lane == 0) wc[b * MM + t] = p;
    }
}

// ---------------------------------------------------------------------------
// Final y + argmax.
// ---------------------------------------------------------------------------
__global__ void y_k(const ushort* __restrict__ inpHi, const ushort* __restrict__ inpLo,
                    const float* __restrict__ W_y, const float* __restrict__ b_y,
                    float* __restrict__ out)
{
    int b = blockIdx.x, lane = threadIdx.x;
    const ushort* hHi = inpHi + (size_t)b * LDA + HOFF;
    const ushort* hLo = inpLo + (size_t)b * LDA + HOFF;
    float a0 = 0, a1 = 0, a2 = 0, a3 = 0;
    for (int r = 0; r < 8; r++) {
        int k = lane + r * 64;
        float hv = bf2f(hHi[k]) + bf2f(hLo[k]);
        a0 += hv * W_y[k];
        a1 += hv * W_y[512 + k];
        a2 += hv * W_y[1024 + k];
        a3 += hv * W_y[1536 + k];
    }
    for (int off = 32; off > 0; off >>= 1) {
        a0 += __shfl_xor(a0, off);
        a1 += __shfl_xor(a1, off);
        a2 += __shfl_xor(a2, off);
        a3 += __shfl_xor(a3, off);
    }
    if (lane == 0) {
        float y0 = a0 + b_y[0], y1 = a1 + b_y[1], y2 = a2 + b_y[2], y3 = a3 + b_y[3];
        out[b * 4 + 0] = y0; out[b * 4 + 1] = y1; out[b * 4 + 2] = y2; out[b * 4 + 3] = y3;
        int best = 0; float bv = y0;
        if (y1 > bv) { bv = y1; best = 1; }
        if (y2 > bv) { bv = y2; best = 2; }
        if (y3 > bv) { bv = y3; best = 3; }
        out[2048 + b] = (float)best;
    }
}

// ---------------------------------------------------------------------------
extern "C" void kernel_launch(void* const* d_in, const int* in_sizes, int n_in,
                              void* d_out, int out_size, void* d_ws, size_t ws_size,
                              hipStream_t stream)
{
    const float* x_seq = (const float*)d_in[0];
    const float* W_enc = (const float*)d_in[1];
    const float* gamma = (const float*)d_in[2];
    const float* beta  = (const float*)d_in[3];
    const float* W_ih  = (const float*)d_in[4];
    const float* W_hh  = (const float*)d_in[5];
    const float* b_ih  = (const float*)d_in[6];
    const float* b_hh  = (const float*)d_in[7];
    const float* W_key = (const float*)d_in[8];
    const float* b_key = (const float*)d_in[9];
    const float* W_g   = (const float*)d_in[10];
    const float* b_g   = (const float*)d_in[11];
    const float* cgain = (const float*)d_in[12];
    const float* cbias = (const float*)d_in[13];
    const float* W_y   = (const float*)d_in[14];
    const float* b_y   = (const float*)d_in[15];

    float* ws    = (float*)d_ws;
    float* z_pad = ws;                          // 2,162,688 f
    float* watt  = z_pad + 2162688;             // 557,568 f
    float* wcv   = watt + 557568;               // 16,896 f
    float* Mk    = wcv + 16896;                 // 4,194,304 f
    float* biasN = Mk + 4194304;                // 2,304 f
    float* cst   = biasN + 2304;                // 262,144 f
    ushort* inpHi0 = (ushort*)(cst + 262144);   // 409,600 us each
    ushort* inpLo0 = inpHi0 + 409600;
    ushort* inpHi1 = inpLo0 + 409600;
    ushort* inpLo1 = inpHi1 + 409600;
    ushort* Whi  = inpLo1 + 409600;             // 1,843,200 us
    ushort* Wlo  = Whi + NB * KPAD;             // 1,843,200 us
    ushort* Behi = Wlo + NB * KPAD;             // 131,072 us
    ushort* Belo = Behi + 131072;               // 131,072 us
    float* P0 = (float*)(Belo + 131072);        // 1,179,648 f (step K-split partials)
    float* P1 = P0 + (size_t)BATCH * NB;        // 1,179,648 f

    // zero c-state + all 4 input ping-pong buffers (contiguous region)
    hipMemsetAsync(cst, 0, 262144 * sizeof(float) + 4 * 409600 * sizeof(ushort), stream);

    prep_w<<<(NB * KPAD + 131072 + 255) / 256, 256, 0, stream>>>(
        W_ih, W_hh, W_key, b_ih, b_hh, b_key, W_enc, Whi, Wlo, Behi, Belo, biasN);

    // encoder: [16384 x 1024] @ [1024 x 128] -> z_pad
    gemm_enc<<<512, 256, 0, stream>>>(x_seq, Behi, Belo, z_pad);
    norm_k<<<512, 128, 0, stream>>>(z_pad, gamma, beta);
    scores_k<<<512, 256, 0, stream>>>(z_pad, cgain, cbias, watt, wcv);

    for (int t = 0; t <= 32; t++) {
        ushort* inHiC = (t & 1) ? inpHi1 : inpHi0;
        ushort* inLoC = (t & 1) ? inpLo1 : inpLo0;
        ushort* inHiN = (t & 1) ? inpHi0 : inpHi1;
        ushort* inLoN = (t & 1) ? inpLo0 : inpLo1;
        gemm_step<<<576, 256, 0, stream>>>(inHiC, inLoC, Whi, Wlo, P0, P1);
        cell_k<<<512, 256, 0, stream>>>(P0, P1, biasN, cst, inHiN, inLoN,
                                        Mk, W_g, b_g, watt, wcv, t);
    }
    y_k<<<512, 64, 0, stream>>>(inpHi1, inpLo1, W_y, b_y, (float*)d_out);
}